// Round 2
// baseline (771.980 us; speedup 1.0000x reference)
//
#include <hip/hip_runtime.h>
#include <hip/hip_bf16.h>
#include <math.h>

#define N_SAMPLES 65536
#define N_OSC 16
#define N_RES 16
#define CPD 16
#define EXPR 2
#define WIN 2048
#define FRAMES 512
#define DEF_FRAMES 256
#define NRE 32          // N_RES * EXPR
#define TILE_M 2048

typedef __hip_bfloat16 bf16;

// Dual-dtype load/store: flag==1 -> buffers are float32, flag==0 -> bf16.
// Explicit branches (not ternary) so the compiler cannot speculate the
// wrong-typed (possibly OOB) load.
static __device__ __forceinline__ float ldv(const void* p, int i, int f32f) {
    if (f32f) return ((const float*)p)[i];
    return __bfloat162float(((const bf16*)p)[i]);
}
static __device__ __forceinline__ void stv(void* p, int i, float v, int f32f) {
    if (f32f) ((float*)p)[i] = v;
    else      ((bf16*)p)[i] = __float2bfloat16(v);
}

// Output element offsets in d_out (concatenated flat, return order)
#define OUT_SUM_OFF 0
#define OUT_ROUTED_OFF 65536
#define OUT_CS_OFF 73728

// ---------------------------------------------------------------- prep (tiny)
__global__ __launch_bounds__(256) void prep_kernel(
    const void* ctrl, const void* defo, const void* noise, const void* attack,
    const void* router, const void* mix, const void* gains,
    const void* damping, const void* mass, const void* tension,
    const void* x0in, const void* amps,
    double* par, float* impulse, float* routed, float* dcur, float* mixg,
    int* rsup, int* gflag, void* out)
{
    int tid = threadIdx.x;
    // ---- dtype detection on `tension` (true values in [4,9]).
    // Reading as bf16 touches <= half the buffer bytes under either dtype.
    __shared__ int sflag;
    if (tid == 0) {
        const bf16* tb = (const bf16*)tension;
        int ok = 1;
        for (int i = 0; i < N_OSC * N_RES * EXPR; ++i) {
            float v = __bfloat162float(tb[i]);
            if (!(v > 3.0f && v < 10.0f)) { ok = 0; break; }
        }
        sflag = ok ? 0 : 1;   // 0 = bf16, 1 = f32
        gflag[0] = sflag;
    }
    __syncthreads();
    const int f32f = sflag;

    // impulse = attack * noise  (16 x 2048)
    for (int i = tid; i < CPD * WIN; i += 256)
        impulse[i] = ldv(attack, i, f32f) * ldv(noise, i, f32f);
    // routed[r,f] = sum_c ctrl[c,f] * router[c,r]  -> also output 1 (before_upsample)
    for (int i = tid; i < N_RES * FRAMES; i += 256) {
        int r = i / FRAMES, f = i - r * FRAMES;
        float s = 0.f;
        for (int c = 0; c < CPD; ++c)
            s += ldv(ctrl, c * FRAMES + f, f32f) * ldv(router, c * N_RES + r, f32f);
        routed[i] = s;
        stv(out, OUT_ROUTED_OFF + i, s, f32f);
    }
    // deformation softmax over EXPR at 256 frames (expr0 gets +1 base)
    for (int i = tid; i < DEF_FRAMES; i += 256) {
        float a0 = 1.0f + ldv(defo, i, f32f);
        float a1 = ldv(defo, DEF_FRAMES + i, f32f);
        float mx = fmaxf(a0, a1);
        float e0 = expf(a0 - mx), e1 = expf(a1 - mx);
        float inv = 1.0f / (e0 + e1);
        dcur[i] = e0 * inv;
        dcur[DEF_FRAMES + i] = e1 * inv;
    }
    // mix softmax + |gains|
    for (int r = tid; r < N_RES; r += 256) {
        float a0 = ldv(mix, 2 * r, f32f), a1 = ldv(mix, 2 * r + 1, f32f);
        float mx = fmaxf(a0, a1);
        float e0 = expf(a0 - mx), e1 = expf(a1 - mx);
        float inv = 1.0f / (e0 + e1);
        mixg[r] = e0 * inv; mixg[16 + r] = e1 * inv;
        mixg[32 + r] = fabsf(ldv(gains, r, f32f));
    }
    for (int i = tid; i < NRE; i += 256) rsup[i] = 0;
    // oscillator constants in f64: input layout [o][r][e], param layout [re][o]
    for (int i = tid; i < N_OSC * N_RES * EXPR; i += 256) {
        int o = i >> 5, r = (i >> 1) & 15, e = i & 1;
        double mm  = 1.0 / (1.0 + exp(-(double)ldv(mass, i, f32f)));
        double dmp = 30.0 / (1.0 + exp(-(double)ldv(damping, i, f32f)));
        double ten = pow(10.0, (double)ldv(tension, i, f32f));
        double x0  = (double)ldv(x0in, i, f32f);
        double amp = (double)ldv(amps, i, f32f);
        double xd  = dmp / (2.0 * mm);
        double om2 = ten - xd * xd;
        if (om2 < 1e-12) om2 = 1e-12;
        double om  = sqrt(om2);
        double phi = atan2(xd * x0, x0 * om);
        double a   = (x0 == 0.0) ? 0.0 : x0 / cos(phi);
        int p = (r * 2 + e) * 16 + o;
        par[p] = xd; par[512 + p] = om; par[1024 + p] = phi; par[1536 + p] = a * amp * amp;
    }
}

// ------------------------------------------------- res materialization (raw) + ssq partials
__global__ __launch_bounds__(256) void res1_kernel(const double* par, float* res, double* dssq_part)
{
    int re = blockIdx.y;
    int tid = threadIdx.x;
    __shared__ double s_xd[16], s_om[16], s_phi[16], s_coef[16];
    if (tid < 16) {
        int p = re * 16 + tid;
        s_xd[tid] = par[p]; s_om[tid] = par[512 + p];
        s_phi[tid] = par[1024 + p]; s_coef[tid] = par[1536 + p];
    }
    __syncthreads();
    const double dt = 10.0 / 65535.0;
    const double inv2pi = 0.15915494309189535;
    const double twopi  = 6.283185307179586;
    double ssq = 0.0;
    float* resc = res + (size_t)re * N_SAMPLES;
    int n0 = blockIdx.x * 8192;
    for (int n = n0 + tid; n < n0 + 8192; n += 256) {
        double t = n * dt;
        float sacc = 0.f;
        for (int o = 0; o < 16; ++o) {
            double arg = s_om[o] * t - s_phi[o];
            double k = rint(arg * inv2pi);
            float red = (float)(arg - k * twopi);       // |red| <= pi, f64-accurate
            float dec = expf((float)(-s_xd[o] * t));    // underflows to 0 harmlessly
            sacc += (float)s_coef[o] * dec * cosf(red);
        }
        if (n < 10) sacc *= (float)n * (1.0f / 9.0f);   // ramp
        resc[n] = sacc;
        ssq += (double)sacc * (double)sacc;
    }
    __shared__ double rb[256];
    rb[tid] = ssq; __syncthreads();
    for (int st = 128; st > 0; st >>= 1) { if (tid < st) rb[tid] += rb[tid + st]; __syncthreads(); }
    if (tid == 0) dssq_part[re * 8 + blockIdx.x] = rb[0];
}

// ------------------------------------------------- normalize + support scan
__global__ __launch_bounds__(256) void res2_kernel(float* res, const double* dssq_part, int* rsup)
{
    int re = blockIdx.y;
    int tid = threadIdx.x;
    double ssq = 0.0;
    for (int j = 0; j < 8; ++j) ssq += dssq_part[re * 8 + j];
    float inv = (float)(1.0 / (sqrt(ssq) + 1e-8));
    float* resc = res + (size_t)re * N_SAMPLES;
    int n0 = blockIdx.x * 8192;
    int mi = 0;
    for (int n = n0 + tid; n < n0 + 8192; n += 256) {
        float v = resc[n] * inv;
        resc[n] = v;
        if (fabsf(v) > 1e-10f) mi = n;
    }
    __shared__ int ib[256];
    ib[tid] = mi; __syncthreads();
    for (int st = 128; st > 0; st >>= 1) { if (tid < st) ib[tid] = max(ib[tid], ib[tid + st]); __syncthreads(); }
    if (tid == 0) atomicMax(&rsup[re], ib[0]);
}

// ------------------------------------------------- routed_c (16-tap sparse conv) + cs
__global__ __launch_bounds__(256) void conv1_kernel(const float* impulse, const float* routed,
                                                    float* routed_c, const int* gflag, void* out)
{
    int f32f = gflag[0];
    int n = blockIdx.x * 256 + threadIdx.x;
    int q = n >> 7, s = n & 127;
    int dkmax = min(q, 15);
    float cs = 0.f;
    for (int c = 0; c < CPD; ++c) {
        const float* ro = routed + c * FRAMES;
        const float* im = impulse + c * WIN + s;
        float acc = 0.f;
        for (int dk = 0; dk <= dkmax; ++dk)
            acc += ro[q - dk] * im[dk << 7];
        routed_c[(size_t)c * N_SAMPLES + n] = acc;
        cs += acc;
    }
    stv(out, OUT_CS_OFF + n, cs, f32f);
}

// ------------------------------------------------- g = impulse (x) res  (2048-tap FIR)
__global__ __launch_bounds__(256) void fir_kernel(const float* res, const float* impulse,
                                                  const int* rsup, float* g)
{
    int re = blockIdx.y;
    int m0 = blockIdx.x * TILE_M;
    int tid = threadIdx.x;
    float* gc = g + (size_t)re * N_SAMPLES;
    if (m0 > rsup[re] + (WIN - 1)) {               // beyond decayed support: g ~ 0
        for (int i = tid; i < TILE_M; i += 256) gc[m0 + i] = 0.0f;
        return;
    }
    __shared__ float imp_s[WIN];
    __shared__ float res_s[WIN + TILE_M];          // 4096 floats
    const float* impc = impulse + (re >> 1) * WIN;
    const float* resc = res + (size_t)re * N_SAMPLES;
    for (int i = tid; i < WIN; i += 256) imp_s[i] = impc[i];
    for (int i = tid; i < WIN + TILE_M; i += 256) {
        int gi = m0 - (WIN - 1) + i;
        res_s[i] = (gi >= 0 && gi < N_SAMPLES) ? resc[gi] : 0.0f;
    }
    __syncthreads();
    int base = tid * 8;
    float acc[8] = {0,0,0,0,0,0,0,0};
    float w[16];
#pragma unroll
    for (int k = 0; k < 8; ++k) w[k] = res_s[base + k];
    for (int p = 0; p < WIN; p += 8) {
#pragma unroll
        for (int k = 0; k < 8; ++k) w[8 + k] = res_s[base + p + 8 + k];
#pragma unroll
        for (int u = 0; u < 8; ++u) {
            float im = imp_s[WIN - 1 - (p + u)];   // broadcast, conflict-free
#pragma unroll
            for (int i = 0; i < 8; ++i) acc[i] += im * w[u + i];
        }
#pragma unroll
        for (int k = 0; k < 8; ++k) w[k] = w[8 + k];
    }
#pragma unroll
    for (int i = 0; i < 8; ++i) gc[m0 + base + i] = acc[i];
}

// ------------------------------------------------- conv = up (x) g, deform mix, tanh sum
__global__ __launch_bounds__(256) void final_kernel(const float* g, const float* routed,
        const float* routed_c, const float* dcur, const float* mixg, const int* rsup,
        const int* gflag, void* out)
{
    __shared__ float routed_s[N_RES * FRAMES];     // 32 KB
    __shared__ float mix_s[48];
    __shared__ int sup_s[NRE];
    int tid = threadIdx.x;
    int f32f = gflag[0];
    for (int i = tid; i < N_RES * FRAMES; i += 256) routed_s[i] = routed[i];
    if (tid < 48) mix_s[tid] = mixg[tid];
    if (tid < NRE) sup_s[tid] = rsup[tid] + (WIN - 1);
    __syncthreads();
    int n = blockIdx.x * 256 + tid;
    // jax.image.resize linear, half-pixel centers, edge clamp
    float xc = ((float)n + 0.5f) * (1.0f / 256.0f) - 0.5f;
    float fl = floorf(xc);
    int i0 = (int)fl;
    float wfr = xc - fl;
    int ia = min(max(i0, 0), DEF_FRAMES - 1);
    int ib2 = min(max(i0 + 1, 0), DEF_FRAMES - 1);
    float d0 = dcur[ia] * (1.0f - wfr) + dcur[ib2] * wfr;
    float d1 = dcur[DEF_FRAMES + ia] * (1.0f - wfr) + dcur[DEF_FRAMES + ib2] * wfr;
    int khi = n >> 7;
    float ssum = 0.f;
    for (int r = 0; r < N_RES; ++r) {
        const float* g0 = g + (size_t)(r * 2) * N_SAMPLES;
        const float* g1 = g + (size_t)(r * 2 + 1) * N_SAMPLES;
        int sup = max(sup_s[r * 2], sup_s[r * 2 + 1]);
        int lo = n - sup;
        int klo = (lo <= 0) ? 0 : ((lo + 127) >> 7);
        const float* ro = routed_s + r * FRAMES;
        float c0 = 0.f, c1 = 0.f;
        for (int k = klo; k <= khi; ++k) {
            float rv = ro[k];
            int idx = n - (k << 7);
            c0 += rv * g0[idx];
            c1 += rv * g1[idx];
        }
        float xmix = d0 * c0 + d1 * c1;
        float xf = mix_s[r] * routed_c[(size_t)r * N_SAMPLES + n] + mix_s[16 + r] * xmix;
        ssum += tanhf(xf * mix_s[32 + r]);
    }
    stv(out, OUT_SUM_OFF + n, ssum, f32f);
}

extern "C" void kernel_launch(void* const* d_in, const int* in_sizes, int n_in,
                              void* d_out, int out_size, void* d_ws, size_t ws_size,
                              hipStream_t stream)
{
    const void* ctrl    = d_in[0];
    const void* defo    = d_in[1];
    const void* noise   = d_in[2];
    const void* attack  = d_in[3];
    const void* router  = d_in[4];
    const void* mix     = d_in[5];
    const void* gains   = d_in[6];
    const void* damping = d_in[7];
    const void* mass    = d_in[8];
    const void* tension = d_in[9];
    const void* x0in    = d_in[10];
    const void* amps    = d_in[11];

    char* ws = (char*)d_ws;
    double* par       = (double*)(ws);             // 2048 d  -> 16384
    double* dssq_part = (double*)(ws + 16384);     // 256 d   -> 18432
    int* gflag        = (int*)(ws + 18432);        //         -> 18560 (pad)
    int* rsup         = (int*)(ws + 18560);        // 32 i    -> 18688
    float* mixg       = (float*)(ws + 18688);      // 48 f    -> 18880
    float* dcur       = (float*)(ws + 18880);      // 512 f   -> 20928 (pad to 20992)
    float* routed     = (float*)(ws + 20992);      // 8192 f  -> 53760
    float* impulse    = (float*)(ws + 53760);      // 32768 f -> 184832 (pad to 196608)
    float* res        = (float*)(ws + 196608);     // 32*65536 f (8 MB)
    float* g          = (float*)(ws + 8585216);    // 32*65536 f (8 MB)
    float* routed_c   = (float*)(ws + 16973824);   // 16*65536 f (4 MB) -> ~20.2 MB total

    prep_kernel<<<dim3(1), dim3(256), 0, stream>>>(
        ctrl, defo, noise, attack, router, mix, gains, damping, mass, tension,
        x0in, amps, par, impulse, routed, dcur, mixg, rsup, gflag, d_out);
    res1_kernel<<<dim3(8, NRE), dim3(256), 0, stream>>>(par, res, dssq_part);
    res2_kernel<<<dim3(8, NRE), dim3(256), 0, stream>>>(res, dssq_part, rsup);
    conv1_kernel<<<dim3(N_SAMPLES / 256), dim3(256), 0, stream>>>(impulse, routed, routed_c, gflag, d_out);
    fir_kernel<<<dim3(N_SAMPLES / TILE_M, NRE), dim3(256), 0, stream>>>(res, impulse, rsup, g);
    final_kernel<<<dim3(N_SAMPLES / 256), dim3(256), 0, stream>>>(g, routed, routed_c, dcur, mixg, rsup, gflag, d_out);
}

// Round 3
// 455.255 us; speedup vs baseline: 1.6957x; 1.6957x over previous
//
#include <hip/hip_runtime.h>
#include <hip/hip_bf16.h>
#include <math.h>

#define N_SAMPLES 65536
#define N_OSC 16
#define N_RES 16
#define CPD 16
#define EXPR 2
#define WIN 2048
#define FRAMES 512
#define DEF_FRAMES 256
#define NRE 32          // N_RES * EXPR
#define TILE_M 2048
#define TAPS 512        // WIN / 4 tap-splits

typedef __hip_bfloat16 bf16;

// Dual-dtype load/store: flag==1 -> buffers are float32, flag==0 -> bf16.
static __device__ __forceinline__ float ldv(const void* p, int i, int f32f) {
    if (f32f) return ((const float*)p)[i];
    return __bfloat162float(((const bf16*)p)[i]);
}
static __device__ __forceinline__ void stv(void* p, int i, float v, int f32f) {
    if (f32f) ((float*)p)[i] = v;
    else      ((bf16*)p)[i] = __float2bfloat16(v);
}

// Output element offsets in d_out (concatenated flat, return order)
#define OUT_SUM_OFF 0
#define OUT_ROUTED_OFF 65536
#define OUT_CS_OFF 73728

// ---------------------------------------------------------------- prep (tiny)
__global__ __launch_bounds__(256) void prep_kernel(
    const void* ctrl, const void* defo, const void* noise, const void* attack,
    const void* router, const void* mix, const void* gains,
    const void* damping, const void* mass, const void* tension,
    const void* x0in, const void* amps,
    double* par, float* impulse, float* routed, float* dcur, float* mixg,
    int* rsup, int* gflag, void* out)
{
    int tid = threadIdx.x;
    // ---- dtype detection on `tension` (true values in [4,9]), parallel.
    __shared__ int sbad;
    if (tid == 0) sbad = 0;
    __syncthreads();
    {
        const bf16* tb = (const bf16*)tension;
        int bad = 0;
        for (int i = tid; i < N_OSC * N_RES * EXPR; i += 256) {
            float v = __bfloat162float(tb[i]);
            if (!(v > 3.0f && v < 10.0f)) bad = 1;
        }
        if (bad) sbad = 1;
    }
    __syncthreads();
    const int f32f = sbad;   // 1 = f32, 0 = bf16
    if (tid == 0) gflag[0] = f32f;

    // impulse = attack * noise  (16 x 2048)
    for (int i = tid; i < CPD * WIN; i += 256)
        impulse[i] = ldv(attack, i, f32f) * ldv(noise, i, f32f);
    // routed[r,f] = sum_c ctrl[c,f] * router[c,r]  -> also output 1 (before_upsample)
    for (int i = tid; i < N_RES * FRAMES; i += 256) {
        int r = i / FRAMES, f = i - r * FRAMES;
        float s = 0.f;
        for (int c = 0; c < CPD; ++c)
            s += ldv(ctrl, c * FRAMES + f, f32f) * ldv(router, c * N_RES + r, f32f);
        routed[i] = s;
        stv(out, OUT_ROUTED_OFF + i, s, f32f);
    }
    // deformation softmax over EXPR at 256 frames (expr0 gets +1 base)
    for (int i = tid; i < DEF_FRAMES; i += 256) {
        float a0 = 1.0f + ldv(defo, i, f32f);
        float a1 = ldv(defo, DEF_FRAMES + i, f32f);
        float mx = fmaxf(a0, a1);
        float e0 = expf(a0 - mx), e1 = expf(a1 - mx);
        float inv = 1.0f / (e0 + e1);
        dcur[i] = e0 * inv;
        dcur[DEF_FRAMES + i] = e1 * inv;
    }
    // mix softmax + |gains|
    for (int r = tid; r < N_RES; r += 256) {
        float a0 = ldv(mix, 2 * r, f32f), a1 = ldv(mix, 2 * r + 1, f32f);
        float mx = fmaxf(a0, a1);
        float e0 = expf(a0 - mx), e1 = expf(a1 - mx);
        float inv = 1.0f / (e0 + e1);
        mixg[r] = e0 * inv; mixg[16 + r] = e1 * inv;
        mixg[32 + r] = fabsf(ldv(gains, r, f32f));
    }
    for (int i = tid; i < NRE; i += 256) rsup[i] = 0;
    // oscillator constants in f64: input layout [o][r][e], param layout [re][o]
    for (int i = tid; i < N_OSC * N_RES * EXPR; i += 256) {
        int o = i >> 5, r = (i >> 1) & 15, e = i & 1;
        double mm  = 1.0 / (1.0 + exp(-(double)ldv(mass, i, f32f)));
        double dmp = 30.0 / (1.0 + exp(-(double)ldv(damping, i, f32f)));
        double ten = pow(10.0, (double)ldv(tension, i, f32f));
        double x0  = (double)ldv(x0in, i, f32f);
        double amp = (double)ldv(amps, i, f32f);
        double xd  = dmp / (2.0 * mm);
        double om2 = ten - xd * xd;
        if (om2 < 1e-12) om2 = 1e-12;
        double om  = sqrt(om2);
        double phi = atan2(xd * x0, x0 * om);
        double a   = (x0 == 0.0) ? 0.0 : x0 / cos(phi);
        int p = (r * 2 + e) * 16 + o;
        par[p] = xd; par[512 + p] = om; par[1024 + p] = phi; par[1536 + p] = a * amp * amp;
    }
}

// ------------------------------------------------- res materialization (raw) + ssq partials
__global__ __launch_bounds__(256) void res1_kernel(const double* par, float* res, double* dssq_part)
{
    int re = blockIdx.y;
    int tid = threadIdx.x;
    __shared__ double s_xd[16], s_om[16], s_phi[16], s_coef[16];
    if (tid < 16) {
        int p = re * 16 + tid;
        s_xd[tid] = par[p]; s_om[tid] = par[512 + p];
        s_phi[tid] = par[1024 + p]; s_coef[tid] = par[1536 + p];
    }
    __syncthreads();
    const double dt = 10.0 / 65535.0;
    const double inv2pi = 0.15915494309189535;
    const double twopi  = 6.283185307179586;
    double ssq = 0.0;
    float* resc = res + (size_t)re * N_SAMPLES;
    int n0 = blockIdx.x * 8192;
    for (int n = n0 + tid; n < n0 + 8192; n += 256) {
        double t = n * dt;
        float sacc = 0.f;
        for (int o = 0; o < 16; ++o) {
            double arg = s_om[o] * t - s_phi[o];
            double k = rint(arg * inv2pi);
            float red = (float)(arg - k * twopi);       // |red| <= pi, f64-accurate
            float dec = expf((float)(-s_xd[o] * t));    // underflows to 0 harmlessly
            sacc += (float)s_coef[o] * dec * cosf(red);
        }
        if (n < 10) sacc *= (float)n * (1.0f / 9.0f);   // ramp
        resc[n] = sacc;
        ssq += (double)sacc * (double)sacc;
    }
    __shared__ double rb[256];
    rb[tid] = ssq; __syncthreads();
    for (int st = 128; st > 0; st >>= 1) { if (tid < st) rb[tid] += rb[tid + st]; __syncthreads(); }
    if (tid == 0) dssq_part[re * 8 + blockIdx.x] = rb[0];
}

// ------------------------------------------------- normalize + support scan
__global__ __launch_bounds__(256) void res2_kernel(float* res, const double* dssq_part, int* rsup)
{
    int re = blockIdx.y;
    int tid = threadIdx.x;
    double ssq = 0.0;
    for (int j = 0; j < 8; ++j) ssq += dssq_part[re * 8 + j];
    float inv = (float)(1.0 / (sqrt(ssq) + 1e-8));
    float* resc = res + (size_t)re * N_SAMPLES;
    int n0 = blockIdx.x * 8192;
    int mi = 0;
    for (int n = n0 + tid; n < n0 + 8192; n += 256) {
        float v = resc[n] * inv;
        resc[n] = v;
        if (fabsf(v) > 1e-10f) mi = n;
    }
    __shared__ int ib[256];
    ib[tid] = mi; __syncthreads();
    for (int st = 128; st > 0; st >>= 1) { if (tid < st) ib[tid] = max(ib[tid], ib[tid + st]); __syncthreads(); }
    if (tid == 0) atomicMax(&rsup[re], ib[0]);
}

// ------------------------------------------------- routed_c (16-tap sparse conv) + cs
__global__ __launch_bounds__(256) void conv1_kernel(const float* impulse, const float* routed,
                                                    float* routed_c, const int* gflag, void* out)
{
    int f32f = gflag[0];
    int n = blockIdx.x * 256 + threadIdx.x;
    int q = n >> 7, s = n & 127;
    int dkmax = min(q, 15);
    float cs = 0.f;
    for (int c = 0; c < CPD; ++c) {
        const float* ro = routed + c * FRAMES;
        const float* im = impulse + c * WIN + s;
        float acc = 0.f;
        for (int dk = 0; dk <= dkmax; ++dk)
            acc += ro[q - dk] * im[dk << 7];
        routed_c[(size_t)c * N_SAMPLES + n] = acc;
        cs += acc;
    }
    stv(out, OUT_CS_OFF + n, cs, f32f);
}

// ------------------------------------------------- zero g (atomics accumulate into it)
__global__ __launch_bounds__(256) void zero_g_kernel(float4* g)
{
    g[blockIdx.x * 256 + threadIdx.x] = float4{0.f, 0.f, 0.f, 0.f};
}

// ------------------------------------------------- g = impulse (x) res  (2048-tap FIR)
// 4-way tap split for parallelism; swizzled LDS window (j -> j + (j>>5)) so
// lane-stride-8 reads hit every bank exactly 2x (free on CDNA4).
__global__ __launch_bounds__(256) void fir_kernel(const float* res, const float* impulse,
                                                  const int* rsup, float* g)
{
    int re = blockIdx.y;
    int tile = blockIdx.x >> 2, s = blockIdx.x & 3;
    int m0 = tile * TILE_M;
    if (m0 > rsup[re] + (WIN - 1) - TAPS * s) return;   // split's res range fully decayed
    int tid = threadIdx.x;
    __shared__ float imp_s[TAPS];
    __shared__ float W[2640];                           // 2560 + swizzle pad
    const float* impc = impulse + (re >> 1) * WIN;
    const float* resc = res + (size_t)re * N_SAMPLES;
    for (int i = tid; i < TAPS; i += 256) imp_s[i] = impc[1536 - TAPS * s + i];
    int gbase = m0 - (WIN - 1) + s * TAPS;
    for (int i = tid; i < 2560; i += 256) {
        int gi = gbase + i;
        float v = (gi >= 0 && gi < N_SAMPLES) ? resc[gi] : 0.0f;
        W[i + (i >> 5)] = v;
    }
    __syncthreads();
    int base = tid * 8;
    float acc[8] = {0,0,0,0,0,0,0,0};
    float w[16];
#pragma unroll
    for (int k = 0; k < 8; ++k) { int j = base + k; w[k] = W[j + (j >> 5)]; }
    for (int p = 0; p < TAPS; p += 8) {
#pragma unroll
        for (int k = 0; k < 8; ++k) { int j = base + p + 8 + k; w[8 + k] = W[j + (j >> 5)]; }
#pragma unroll
        for (int u = 0; u < 8; ++u) {
            float im = imp_s[511 - p - u];              // wave-uniform broadcast
#pragma unroll
            for (int i = 0; i < 8; ++i) acc[i] += im * w[u + i];
        }
#pragma unroll
        for (int k = 0; k < 8; ++k) w[k] = w[8 + k];
    }
    float* gc = g + (size_t)re * N_SAMPLES + m0 + base;
#pragma unroll
    for (int i = 0; i < 8; ++i) atomicAdd(gc + i, acc[i]);
}

// ------------------------------------------------- g (f32) -> gh (bf16), halves final's traffic
__global__ __launch_bounds__(256) void g2h_kernel(const float* g, bf16* gh)
{
    int i4 = blockIdx.x * 256 + threadIdx.x;
    float4 v = ((const float4*)g)[i4];
    union { bf16 b[4]; ushort4 u; } t;
    t.b[0] = __float2bfloat16(v.x); t.b[1] = __float2bfloat16(v.y);
    t.b[2] = __float2bfloat16(v.z); t.b[3] = __float2bfloat16(v.w);
    ((ushort4*)gh)[i4] = t.u;
}

// ------------------------------------------------- conv = up (x) g, deform mix, tanh sum
// 64 samples x 4 r-groups per block -> 1024 blocks (4/CU), LDS reduce over r-groups.
__global__ __launch_bounds__(256) void final_kernel(const bf16* gh, const float* routed,
        const float* routed_c, const float* dcur, const float* mixg, const int* rsup,
        const int* gflag, void* out)
{
    __shared__ float routed_s[N_RES * FRAMES];     // 32 KB
    __shared__ float dcur_s[2 * DEF_FRAMES];
    __shared__ float mix_s[48];
    __shared__ int sup_s[NRE];
    __shared__ float part[256];
    int tid = threadIdx.x;
    int f32f = gflag[0];
    for (int i = tid; i < N_RES * FRAMES; i += 256) routed_s[i] = routed[i];
    for (int i = tid; i < 2 * DEF_FRAMES; i += 256) dcur_s[i] = dcur[i];
    if (tid < 48) mix_s[tid] = mixg[tid];
    if (tid < NRE) sup_s[tid] = rsup[tid] + (WIN - 1);
    __syncthreads();
    int nl = tid & 63, rg = tid >> 6;
    int n = blockIdx.x * 64 + nl;
    // jax.image.resize linear, half-pixel centers, edge clamp
    float xc = ((float)n + 0.5f) * (1.0f / 256.0f) - 0.5f;
    float fl = floorf(xc);
    int i0 = (int)fl;
    float wfr = xc - fl;
    int ia = min(max(i0, 0), DEF_FRAMES - 1);
    int ib2 = min(max(i0 + 1, 0), DEF_FRAMES - 1);
    float d0 = dcur_s[ia] * (1.0f - wfr) + dcur_s[ib2] * wfr;
    float d1 = dcur_s[DEF_FRAMES + ia] * (1.0f - wfr) + dcur_s[DEF_FRAMES + ib2] * wfr;
    int khi = n >> 7;
    float partial = 0.f;
    for (int rr = 0; rr < 4; ++rr) {
        int r = rg * 4 + rr;
        const bf16* g0 = gh + (size_t)(r * 2) * N_SAMPLES;
        const bf16* g1 = gh + (size_t)(r * 2 + 1) * N_SAMPLES;
        int sup = max(sup_s[r * 2], sup_s[r * 2 + 1]);
        int lo = n - sup;
        int klo = (lo <= 0) ? 0 : ((lo + 127) >> 7);
        const float* ro = routed_s + r * FRAMES;
        float c0 = 0.f, c1 = 0.f;
        for (int k = klo; k <= khi; ++k) {
            float rv = ro[k];
            int idx = n - (k << 7);
            c0 += rv * __bfloat162float(g0[idx]);
            c1 += rv * __bfloat162float(g1[idx]);
        }
        float xmix = d0 * c0 + d1 * c1;
        float xf = mix_s[r] * routed_c[(size_t)r * N_SAMPLES + n] + mix_s[16 + r] * xmix;
        partial += tanhf(xf * mix_s[32 + r]);
    }
    part[tid] = partial;
    __syncthreads();
    if (tid < 64) {
        float ssum = part[tid] + part[tid + 64] + part[tid + 128] + part[tid + 192];
        stv(out, OUT_SUM_OFF + blockIdx.x * 64 + tid, ssum, f32f);
    }
}

extern "C" void kernel_launch(void* const* d_in, const int* in_sizes, int n_in,
                              void* d_out, int out_size, void* d_ws, size_t ws_size,
                              hipStream_t stream)
{
    const void* ctrl    = d_in[0];
    const void* defo    = d_in[1];
    const void* noise   = d_in[2];
    const void* attack  = d_in[3];
    const void* router  = d_in[4];
    const void* mix     = d_in[5];
    const void* gains   = d_in[6];
    const void* damping = d_in[7];
    const void* mass    = d_in[8];
    const void* tension = d_in[9];
    const void* x0in    = d_in[10];
    const void* amps    = d_in[11];

    char* ws = (char*)d_ws;
    double* par       = (double*)(ws);             // 2048 d  -> 16384
    double* dssq_part = (double*)(ws + 16384);     // 256 d   -> 18432
    int* gflag        = (int*)(ws + 18432);        //         -> 18560 (pad)
    int* rsup         = (int*)(ws + 18560);        // 32 i    -> 18688
    float* mixg       = (float*)(ws + 18688);      // 48 f    -> 18880
    float* dcur       = (float*)(ws + 18880);      // 512 f   -> 20928 (pad to 20992)
    float* routed     = (float*)(ws + 20992);      // 8192 f  -> 53760
    float* impulse    = (float*)(ws + 53760);      // 32768 f -> 184832 (pad to 196608)
    float* res        = (float*)(ws + 196608);     // 32*65536 f (8 MB)
    float* g          = (float*)(ws + 8585216);    // 32*65536 f (8 MB)
    float* routed_c   = (float*)(ws + 16973824);   // 16*65536 f (4 MB) -> ~20.2 MB total
    bf16* gh          = (bf16*)res;                // aliases res (dead after fir): 4 MB

    prep_kernel<<<dim3(1), dim3(256), 0, stream>>>(
        ctrl, defo, noise, attack, router, mix, gains, damping, mass, tension,
        x0in, amps, par, impulse, routed, dcur, mixg, rsup, gflag, d_out);
    res1_kernel<<<dim3(8, NRE), dim3(256), 0, stream>>>(par, res, dssq_part);
    res2_kernel<<<dim3(8, NRE), dim3(256), 0, stream>>>(res, dssq_part, rsup);
    conv1_kernel<<<dim3(N_SAMPLES / 256), dim3(256), 0, stream>>>(impulse, routed, routed_c, gflag, d_out);
    zero_g_kernel<<<dim3(2048), dim3(256), 0, stream>>>((float4*)g);
    fir_kernel<<<dim3((N_SAMPLES / TILE_M) * 4, NRE), dim3(256), 0, stream>>>(res, impulse, rsup, g);
    g2h_kernel<<<dim3(2048), dim3(256), 0, stream>>>(g, gh);
    final_kernel<<<dim3(N_SAMPLES / 64), dim3(256), 0, stream>>>(gh, routed, routed_c, dcur, mixg, rsup, gflag, d_out);
}

// Round 4
// 360.049 us; speedup vs baseline: 2.1441x; 1.2644x over previous
//
#include <hip/hip_runtime.h>
#include <hip/hip_bf16.h>
#include <math.h>

#define N_SAMPLES 65536
#define N_OSC 16
#define N_RES 16
#define CPD 16
#define EXPR 2
#define WIN 2048
#define FRAMES 512
#define DEF_FRAMES 256
#define NRE 32          // N_RES * EXPR
#define TILE_M 2048
#define TAPS 512        // WIN / 4 tap-splits
#define R1TILE 1024
#define R1TILES (N_SAMPLES / R1TILE)   // 64

typedef __hip_bfloat16 bf16;

// Dual-dtype load/store: flag==1 -> buffers are float32, flag==0 -> bf16.
static __device__ __forceinline__ float ldv(const void* p, int i, int f32f) {
    if (f32f) return ((const float*)p)[i];
    return __bfloat162float(((const bf16*)p)[i]);
}
static __device__ __forceinline__ void stv(void* p, int i, float v, int f32f) {
    if (f32f) ((float*)p)[i] = v;
    else      ((bf16*)p)[i] = __float2bfloat16(v);
}

// Output element offsets in d_out (concatenated flat, return order)
#define OUT_SUM_OFF 0
#define OUT_ROUTED_OFF 65536
#define OUT_CS_OFF 73728

#define DT_F64 (10.0 / 65535.0)
#define INV2PI 0.15915494309189535

// ---------------------------------------------------------------- prep (tiny)
__global__ __launch_bounds__(256) void prep_kernel(
    const void* ctrl, const void* defo, const void* noise, const void* attack,
    const void* router, const void* mix, const void* gains,
    const void* damping, const void* mass, const void* tension,
    const void* x0in, const void* amps,
    double* par, float* impulse, float* routed, float* dcur, float* mixg,
    int* rsup, int* nbound, int* gflag, void* out)
{
    int tid = threadIdx.x;
    // ---- dtype detection on `tension` (true values in [4,9]), parallel.
    __shared__ int sbad;
    if (tid == 0) sbad = 0;
    __syncthreads();
    {
        const bf16* tb = (const bf16*)tension;
        int bad = 0;
        for (int i = tid; i < N_OSC * N_RES * EXPR; i += 256) {
            float v = __bfloat162float(tb[i]);
            if (!(v > 3.0f && v < 10.0f)) bad = 1;
        }
        if (bad) sbad = 1;
    }
    __syncthreads();
    const int f32f = sbad;   // 1 = f32, 0 = bf16
    if (tid == 0) gflag[0] = f32f;

    // impulse = attack * noise  (16 x 2048)
    for (int i = tid; i < CPD * WIN; i += 256)
        impulse[i] = ldv(attack, i, f32f) * ldv(noise, i, f32f);
    // routed[r,f] = sum_c ctrl[c,f] * router[c,r]  -> also output 1 (before_upsample)
    for (int i = tid; i < N_RES * FRAMES; i += 256) {
        int r = i / FRAMES, f = i - r * FRAMES;
        float s = 0.f;
        for (int c = 0; c < CPD; ++c)
            s += ldv(ctrl, c * FRAMES + f, f32f) * ldv(router, c * N_RES + r, f32f);
        routed[i] = s;
        stv(out, OUT_ROUTED_OFF + i, s, f32f);
    }
    // deformation softmax over EXPR at 256 frames (expr0 gets +1 base)
    for (int i = tid; i < DEF_FRAMES; i += 256) {
        float a0 = 1.0f + ldv(defo, i, f32f);
        float a1 = ldv(defo, DEF_FRAMES + i, f32f);
        float mx = fmaxf(a0, a1);
        float e0 = expf(a0 - mx), e1 = expf(a1 - mx);
        float inv = 1.0f / (e0 + e1);
        dcur[i] = e0 * inv;
        dcur[DEF_FRAMES + i] = e1 * inv;
    }
    // mix softmax + |gains|
    for (int r = tid; r < N_RES; r += 256) {
        float a0 = ldv(mix, 2 * r, f32f), a1 = ldv(mix, 2 * r + 1, f32f);
        float mx = fmaxf(a0, a1);
        float e0 = expf(a0 - mx), e1 = expf(a1 - mx);
        float inv = 1.0f / (e0 + e1);
        mixg[r] = e0 * inv; mixg[16 + r] = e1 * inv;
        mixg[32 + r] = fabsf(ldv(gains, r, f32f));
    }
    for (int i = tid; i < NRE; i += 256) rsup[i] = 0;
    // oscillator constants in f64: input layout [o][r][e], param layout [re][o]
    for (int i = tid; i < N_OSC * N_RES * EXPR; i += 256) {
        int o = i >> 5, r = (i >> 1) & 15, e = i & 1;
        double mm  = 1.0 / (1.0 + exp(-(double)ldv(mass, i, f32f)));
        double dmp = 30.0 / (1.0 + exp(-(double)ldv(damping, i, f32f)));
        double ten = pow(10.0, (double)ldv(tension, i, f32f));
        double x0  = (double)ldv(x0in, i, f32f);
        double amp = (double)ldv(amps, i, f32f);
        double xd  = dmp / (2.0 * mm);
        double om2 = ten - xd * xd;
        if (om2 < 1e-12) om2 = 1e-12;
        double om  = sqrt(om2);
        double phi = atan2(xd * x0, x0 * om);
        double a   = (x0 == 0.0) ? 0.0 : x0 / cos(phi);
        int p = (r * 2 + e) * 16 + o;
        par[p] = xd; par[512 + p] = om; par[1024 + p] = phi; par[1536 + p] = a * amp * amp;
    }
    __syncthreads();   // par visible block-wide
    // decay support bound per re: e^-35 relative decay (~6e-16), beyond is noise
    if (tid < NRE) {
        double mt = 0.0;
        for (int o = 0; o < 16; ++o) {
            double xd = par[tid * 16 + o];
            double t = 35.0 / xd;
            if (t > mt) mt = t;
        }
        int nb = (int)(mt * 6553.5) + 1;
        if (nb > N_SAMPLES - 1) nb = N_SAMPLES - 1;
        nbound[tid] = nb;
    }
}

// ------------------------------------------------- res materialization (incremental) + ssq partials
__global__ __launch_bounds__(256) void res1_kernel(const double* par, const int* nbound,
                                                   float* res, double* dssq_part)
{
    int re = blockIdx.y;
    int tile = blockIdx.x;
    int n0 = tile * R1TILE;
    int tid = threadIdx.x;
    float* resc = res + (size_t)re * N_SAMPLES;
    if (n0 > nbound[re]) {                       // fully decayed: zero-fill
        ((float4*)(resc + n0))[tid] = float4{0.f, 0.f, 0.f, 0.f};
        if (tid == 0) dssq_part[re * R1TILES + tile] = 0.0;
        return;
    }
    __shared__ double s_om[16], s_phi[16], s_xd[16], s_coef[16];
    __shared__ float s_drev[16], s_decf[16];
    if (tid < 16) {
        int pi = re * 16 + tid;
        double xd = par[pi], om = par[512 + pi];
        s_xd[tid] = xd; s_om[tid] = om;
        s_phi[tid] = par[1024 + pi]; s_coef[tid] = par[1536 + pi];
        s_drev[tid] = (float)(om * DT_F64 * INV2PI);   // < 0.77 rev/step
        s_decf[tid] = (float)exp(-xd * DT_F64);
    }
    __syncthreads();
    int ns = n0 + tid * 4;
    double t0 = (double)ns * DT_F64;
    float p[16], cd[16], drev[16], decf[16];
#pragma unroll
    for (int o = 0; o < 16; ++o) {
        double arg = s_om[o] * t0 - s_phi[o];
        double rev = arg * INV2PI;
        rev -= rint(rev);
        p[o] = (float)rev;                              // [-0.5, 0.5] revolutions
        cd[o] = (float)s_coef[o] * expf((float)(-s_xd[o] * t0));
        drev[o] = s_drev[o]; decf[o] = s_decf[o];
    }
    float vals[4];
    double ssq = 0.0;
#pragma unroll
    for (int j = 0; j < 4; ++j) {
        float acc = 0.f;
#pragma unroll
        for (int o = 0; o < 16; ++o) {
            acc += cd[o] * __builtin_amdgcn_cosf(p[o]);  // cos(2*pi*p)
            cd[o] *= decf[o];
            float pn = p[o] + drev[o];
            p[o] = pn - floorf(pn);
        }
        int n = ns + j;
        if (n < 10) acc *= (float)n * (1.0f / 9.0f);     // ramp
        vals[j] = acc;
        ssq += (double)acc * (double)acc;
    }
    *(float4*)(resc + ns) = float4{vals[0], vals[1], vals[2], vals[3]};
    __shared__ double rb[256];
    rb[tid] = ssq; __syncthreads();
    for (int st = 128; st > 0; st >>= 1) { if (tid < st) rb[tid] += rb[tid + st]; __syncthreads(); }
    if (tid == 0) dssq_part[re * R1TILES + tile] = rb[0];
}

// ------------------------------------------------- normalize + support scan
__global__ __launch_bounds__(256) void res2_kernel(float* res, const double* dssq_part,
                                                   const int* nbound, int* rsup)
{
    int re = blockIdx.y;
    int n0 = blockIdx.x * R1TILE;
    if (n0 > nbound[re]) return;                 // region is exact zeros
    int tid = threadIdx.x;
    double ssq = 0.0;
    for (int j = 0; j < R1TILES; ++j) ssq += dssq_part[re * R1TILES + j];
    float inv = (float)(1.0 / (sqrt(ssq) + 1e-8));
    float* resc = res + (size_t)re * N_SAMPLES;
    int n = n0 + tid * 4;
    float4 v = *(float4*)(resc + n);
    v.x *= inv; v.y *= inv; v.z *= inv; v.w *= inv;
    *(float4*)(resc + n) = v;
    int mi = 0;
    if (fabsf(v.x) > 1e-10f) mi = n;
    if (fabsf(v.y) > 1e-10f) mi = n + 1;
    if (fabsf(v.z) > 1e-10f) mi = n + 2;
    if (fabsf(v.w) > 1e-10f) mi = n + 3;
    __shared__ int ib[256];
    ib[tid] = mi; __syncthreads();
    for (int st = 128; st > 0; st >>= 1) { if (tid < st) ib[tid] = max(ib[tid], ib[tid + st]); __syncthreads(); }
    if (tid == 0 && ib[0] > 0) atomicMax(&rsup[re], ib[0]);
}

// ------------------------------------------------- routed_c (16-tap sparse conv) + cs
__global__ __launch_bounds__(256) void conv1_kernel(const float* impulse, const float* routed,
                                                    float* routed_c, const int* gflag, void* out)
{
    int f32f = gflag[0];
    int n = blockIdx.x * 256 + threadIdx.x;
    int q = n >> 7, s = n & 127;
    int dkmax = min(q, 15);
    float cs = 0.f;
    for (int c = 0; c < CPD; ++c) {
        const float* ro = routed + c * FRAMES;
        const float* im = impulse + c * WIN + s;
        float acc = 0.f;
        for (int dk = 0; dk <= dkmax; ++dk)
            acc += ro[q - dk] * im[dk << 7];
        routed_c[(size_t)c * N_SAMPLES + n] = acc;
        cs += acc;
    }
    stv(out, OUT_CS_OFF + n, cs, f32f);
}

// ------------------------------------------------- zero g (atomics accumulate into it)
__global__ __launch_bounds__(256) void zero_g_kernel(float4* g)
{
    g[blockIdx.x * 256 + threadIdx.x] = float4{0.f, 0.f, 0.f, 0.f};
}

// ------------------------------------------------- g = impulse (x) res  (2048-tap FIR)
// 4-way tap split for parallelism; swizzled LDS window (j -> j + (j>>5)) so
// lane-stride-8 reads hit every bank exactly 2x (free on CDNA4).
__global__ __launch_bounds__(256) void fir_kernel(const float* res, const float* impulse,
                                                  const int* rsup, float* g)
{
    int re = blockIdx.y;
    int tile = blockIdx.x >> 2, s = blockIdx.x & 3;
    int m0 = tile * TILE_M;
    if (m0 > rsup[re] + (WIN - 1) - TAPS * s) return;   // split's res range fully decayed
    int tid = threadIdx.x;
    __shared__ float imp_s[TAPS];
    __shared__ float W[2640];                           // 2560 + swizzle pad
    const float* impc = impulse + (re >> 1) * WIN;
    const float* resc = res + (size_t)re * N_SAMPLES;
    for (int i = tid; i < TAPS; i += 256) imp_s[i] = impc[1536 - TAPS * s + i];
    int gbase = m0 - (WIN - 1) + s * TAPS;
    for (int i = tid; i < 2560; i += 256) {
        int gi = gbase + i;
        float v = (gi >= 0 && gi < N_SAMPLES) ? resc[gi] : 0.0f;
        W[i + (i >> 5)] = v;
    }
    __syncthreads();
    int base = tid * 8;
    float acc[8] = {0,0,0,0,0,0,0,0};
    float w[16];
#pragma unroll
    for (int k = 0; k < 8; ++k) { int j = base + k; w[k] = W[j + (j >> 5)]; }
    for (int p = 0; p < TAPS; p += 8) {
#pragma unroll
        for (int k = 0; k < 8; ++k) { int j = base + p + 8 + k; w[8 + k] = W[j + (j >> 5)]; }
#pragma unroll
        for (int u = 0; u < 8; ++u) {
            float im = imp_s[511 - p - u];              // wave-uniform broadcast
#pragma unroll
            for (int i = 0; i < 8; ++i) acc[i] += im * w[u + i];
        }
#pragma unroll
        for (int k = 0; k < 8; ++k) w[k] = w[8 + k];
    }
    float* gc = g + (size_t)re * N_SAMPLES + m0 + base;
#pragma unroll
    for (int i = 0; i < 8; ++i) atomicAdd(gc + i, acc[i]);
}

// ------------------------------------------------- g (f32) -> gh (bf16), halves final's traffic
__global__ __launch_bounds__(256) void g2h_kernel(const float* g, bf16* gh)
{
    int i4 = blockIdx.x * 256 + threadIdx.x;
    float4 v = ((const float4*)g)[i4];
    union { bf16 b[4]; ushort4 u; } t;
    t.b[0] = __float2bfloat16(v.x); t.b[1] = __float2bfloat16(v.y);
    t.b[2] = __float2bfloat16(v.z); t.b[3] = __float2bfloat16(v.w);
    ((ushort4*)gh)[i4] = t.u;
}

// ------------------------------------------------- conv = up (x) g, deform mix, tanh sum
// 64 samples x 4 r-groups per block -> 1024 blocks (4/CU), LDS reduce over r-groups.
__global__ __launch_bounds__(256) void final_kernel(const bf16* gh, const float* routed,
        const float* routed_c, const float* dcur, const float* mixg, const int* rsup,
        const int* gflag, void* out)
{
    __shared__ float routed_s[N_RES * FRAMES];     // 32 KB
    __shared__ float dcur_s[2 * DEF_FRAMES];
    __shared__ float mix_s[48];
    __shared__ int sup_s[NRE];
    __shared__ float part[256];
    int tid = threadIdx.x;
    int f32f = gflag[0];
    for (int i = tid; i < N_RES * FRAMES; i += 256) routed_s[i] = routed[i];
    for (int i = tid; i < 2 * DEF_FRAMES; i += 256) dcur_s[i] = dcur[i];
    if (tid < 48) mix_s[tid] = mixg[tid];
    if (tid < NRE) sup_s[tid] = rsup[tid] + (WIN - 1);
    __syncthreads();
    int nl = tid & 63, rg = tid >> 6;
    int n = blockIdx.x * 64 + nl;
    // jax.image.resize linear, half-pixel centers, edge clamp
    float xc = ((float)n + 0.5f) * (1.0f / 256.0f) - 0.5f;
    float fl = floorf(xc);
    int i0 = (int)fl;
    float wfr = xc - fl;
    int ia = min(max(i0, 0), DEF_FRAMES - 1);
    int ib2 = min(max(i0 + 1, 0), DEF_FRAMES - 1);
    float d0 = dcur_s[ia] * (1.0f - wfr) + dcur_s[ib2] * wfr;
    float d1 = dcur_s[DEF_FRAMES + ia] * (1.0f - wfr) + dcur_s[DEF_FRAMES + ib2] * wfr;
    int khi = n >> 7;
    float partial = 0.f;
    for (int rr = 0; rr < 4; ++rr) {
        int r = rg * 4 + rr;
        const bf16* g0 = gh + (size_t)(r * 2) * N_SAMPLES;
        const bf16* g1 = gh + (size_t)(r * 2 + 1) * N_SAMPLES;
        int sup = max(sup_s[r * 2], sup_s[r * 2 + 1]);
        int lo = n - sup;
        int klo = (lo <= 0) ? 0 : ((lo + 127) >> 7);
        const float* ro = routed_s + r * FRAMES;
        float c0 = 0.f, c1 = 0.f;
        for (int k = klo; k <= khi; ++k) {
            float rv = ro[k];
            int idx = n - (k << 7);
            c0 += rv * __bfloat162float(g0[idx]);
            c1 += rv * __bfloat162float(g1[idx]);
        }
        float xmix = d0 * c0 + d1 * c1;
        float xf = mix_s[r] * routed_c[(size_t)r * N_SAMPLES + n] + mix_s[16 + r] * xmix;
        partial += tanhf(xf * mix_s[32 + r]);
    }
    part[tid] = partial;
    __syncthreads();
    if (tid < 64) {
        float ssum = part[tid] + part[tid + 64] + part[tid + 128] + part[tid + 192];
        stv(out, OUT_SUM_OFF + blockIdx.x * 64 + tid, ssum, f32f);
    }
}

extern "C" void kernel_launch(void* const* d_in, const int* in_sizes, int n_in,
                              void* d_out, int out_size, void* d_ws, size_t ws_size,
                              hipStream_t stream)
{
    const void* ctrl    = d_in[0];
    const void* defo    = d_in[1];
    const void* noise   = d_in[2];
    const void* attack  = d_in[3];
    const void* router  = d_in[4];
    const void* mix     = d_in[5];
    const void* gains   = d_in[6];
    const void* damping = d_in[7];
    const void* mass    = d_in[8];
    const void* tension = d_in[9];
    const void* x0in    = d_in[10];
    const void* amps    = d_in[11];

    char* ws = (char*)d_ws;
    double* par       = (double*)(ws);             // 2048 d  -> 16384
    double* dssq_part = (double*)(ws + 16384);     // 2048 d  -> 32768
    int* gflag        = (int*)(ws + 32768);        //         -> 32896
    int* rsup         = (int*)(ws + 32896);        // 32 i    -> 33024
    int* nbound       = (int*)(ws + 33024);        // 32 i    -> 33152
    float* mixg       = (float*)(ws + 33152);      // 48 f    -> 33344
    float* dcur       = (float*)(ws + 33344);      // 512 f   -> 35392
    float* routed     = (float*)(ws + 35456);      // 8192 f  -> 68224
    float* impulse    = (float*)(ws + 68224);      // 32768 f -> 199296 (pad to 262144)
    float* res        = (float*)(ws + 262144);     // 32*65536 f (8 MB) -> 8650752
    float* g          = (float*)(ws + 8650752);    // 32*65536 f (8 MB) -> 17039360
    float* routed_c   = (float*)(ws + 17039360);   // 16*65536 f (4 MB) -> 21233664
    bf16* gh          = (bf16*)res;                // aliases res (dead after fir): 4 MB

    prep_kernel<<<dim3(1), dim3(256), 0, stream>>>(
        ctrl, defo, noise, attack, router, mix, gains, damping, mass, tension,
        x0in, amps, par, impulse, routed, dcur, mixg, rsup, nbound, gflag, d_out);
    res1_kernel<<<dim3(R1TILES, NRE), dim3(256), 0, stream>>>(par, nbound, res, dssq_part);
    res2_kernel<<<dim3(R1TILES, NRE), dim3(256), 0, stream>>>(res, dssq_part, nbound, rsup);
    conv1_kernel<<<dim3(N_SAMPLES / 256), dim3(256), 0, stream>>>(impulse, routed, routed_c, gflag, d_out);
    zero_g_kernel<<<dim3(2048), dim3(256), 0, stream>>>((float4*)g);
    fir_kernel<<<dim3((N_SAMPLES / TILE_M) * 4, NRE), dim3(256), 0, stream>>>(res, impulse, rsup, g);
    g2h_kernel<<<dim3(2048), dim3(256), 0, stream>>>(g, gh);
    final_kernel<<<dim3(N_SAMPLES / 64), dim3(256), 0, stream>>>(gh, routed, routed_c, dcur, mixg, rsup, gflag, d_out);
}

// Round 5
// 295.015 us; speedup vs baseline: 2.6167x; 1.2204x over previous
//
#include <hip/hip_runtime.h>
#include <hip/hip_bf16.h>
#include <math.h>

#define N_SAMPLES 65536
#define N_OSC 16
#define N_RES 16
#define CPD 16
#define EXPR 2
#define WIN 2048
#define FRAMES 512
#define DEF_FRAMES 256
#define NRE 32          // N_RES * EXPR
#define TILE_M 2048
#define TAPS 512        // WIN / 4 tap-splits
#define R1TILE 1024
#define R1TILES (N_SAMPLES / R1TILE)   // 64

typedef __hip_bfloat16 bf16;

// Dual-dtype load/store: flag==1 -> buffers are float32, flag==0 -> bf16.
static __device__ __forceinline__ float ldv(const void* p, int i, int f32f) {
    if (f32f) return ((const float*)p)[i];
    return __bfloat162float(((const bf16*)p)[i]);
}
static __device__ __forceinline__ void stv(void* p, int i, float v, int f32f) {
    if (f32f) ((float*)p)[i] = v;
    else      ((bf16*)p)[i] = __float2bfloat16(v);
}

// Output element offsets in d_out (concatenated flat, return order)
#define OUT_SUM_OFF 0
#define OUT_ROUTED_OFF 65536
#define OUT_CS_OFF 73728

#define DT_F64 (10.0 / 65535.0)
#define INV2PI 0.15915494309189535

// ---------------------------------------------------------------- prep (parallel, 98 blocks)
// b[0,32):  routed matmul, 256 outputs/block
// b[32,64): impulse, 1024 elems/block
// b==64:    deformation softmax;  b==65: mix/gains/rsup/gflag
// b[66,98): oscillator params + nbound for re = b-66 (16-wide f64)
__global__ __launch_bounds__(256) void prep_kernel(
    const void* ctrl, const void* defo, const void* noise, const void* attack,
    const void* router, const void* mix, const void* gains,
    const void* damping, const void* mass, const void* tension,
    const void* x0in, const void* amps,
    double* par, float* impulse, float* routed, float* dcur, float* mixg,
    int* rsup, int* nbound, int* gflag, void* out)
{
    int tid = threadIdx.x;
    int b = blockIdx.x;
    // ---- dtype detection on `tension` (true values in [4,9]), per-block.
    __shared__ int sbad;
    if (tid == 0) sbad = 0;
    __syncthreads();
    {
        const bf16* tb = (const bf16*)tension;
        int bad = 0;
        for (int i = tid; i < N_OSC * N_RES * EXPR; i += 256) {
            float v = __bfloat162float(tb[i]);
            if (!(v > 3.0f && v < 10.0f)) bad = 1;
        }
        if (bad) sbad = 1;
    }
    __syncthreads();
    const int f32f = sbad;   // 1 = f32, 0 = bf16

    if (b < 32) {
        // routed[r,f] = sum_c ctrl[c,f] * router[c,r]  -> also output 1
        int r = b >> 1;
        int f = ((b & 1) << 8) + tid;
        float s = 0.f;
#pragma unroll
        for (int c = 0; c < CPD; ++c)
            s += ldv(ctrl, c * FRAMES + f, f32f) * ldv(router, c * N_RES + r, f32f);
        int i = r * FRAMES + f;
        routed[i] = s;
        stv(out, OUT_ROUTED_OFF + i, s, f32f);
    } else if (b < 64) {
        // impulse = attack * noise  (16 x 2048)
        int base = (b - 32) * 1024 + tid * 4;
#pragma unroll
        for (int j = 0; j < 4; ++j) {
            int i = base + j;
            impulse[i] = ldv(attack, i, f32f) * ldv(noise, i, f32f);
        }
    } else if (b == 64) {
        // deformation softmax over EXPR at 256 frames (expr0 gets +1 base)
        int i = tid;
        if (i < DEF_FRAMES) {
            float a0 = 1.0f + ldv(defo, i, f32f);
            float a1 = ldv(defo, DEF_FRAMES + i, f32f);
            float mx = fmaxf(a0, a1);
            float e0 = expf(a0 - mx), e1 = expf(a1 - mx);
            float inv = 1.0f / (e0 + e1);
            dcur[i] = e0 * inv;
            dcur[DEF_FRAMES + i] = e1 * inv;
        }
    } else if (b == 65) {
        // mix softmax + |gains| + zero rsup + publish gflag
        if (tid < N_RES) {
            int r = tid;
            float a0 = ldv(mix, 2 * r, f32f), a1 = ldv(mix, 2 * r + 1, f32f);
            float mx = fmaxf(a0, a1);
            float e0 = expf(a0 - mx), e1 = expf(a1 - mx);
            float inv = 1.0f / (e0 + e1);
            mixg[r] = e0 * inv; mixg[16 + r] = e1 * inv;
            mixg[32 + r] = fabsf(ldv(gains, r, f32f));
        }
        if (tid < NRE) rsup[tid] = 0;
        if (tid == 0) gflag[0] = f32f;
    } else {
        // oscillator constants in f64 for re = b-66; input layout [o][r][e]
        int re = b - 66;
        __shared__ double s_xd[16];
        if (tid < 16) {
            int o = tid;
            int i = o * 32 + re;
            double mm  = 1.0 / (1.0 + exp(-(double)ldv(mass, i, f32f)));
            double dmp = 30.0 / (1.0 + exp(-(double)ldv(damping, i, f32f)));
            double ten = pow(10.0, (double)ldv(tension, i, f32f));
            double x0  = (double)ldv(x0in, i, f32f);
            double amp = (double)ldv(amps, i, f32f);
            double xd  = dmp / (2.0 * mm);
            double om2 = ten - xd * xd;
            if (om2 < 1e-12) om2 = 1e-12;
            double om  = sqrt(om2);
            double phi = atan2(xd * x0, x0 * om);
            double a   = (x0 == 0.0) ? 0.0 : x0 / cos(phi);
            int p = re * 16 + o;
            par[p] = xd; par[512 + p] = om; par[1024 + p] = phi; par[1536 + p] = a * amp * amp;
            s_xd[o] = xd;
        }
        __syncthreads();
        // decay support bound: e^-35 relative decay (~6e-16), beyond is noise
        if (tid == 0) {
            double mt = 0.0;
            for (int o = 0; o < 16; ++o) {
                double t = 35.0 / s_xd[o];
                if (t > mt) mt = t;
            }
            int nb = (int)(mt * 6553.5) + 1;
            if (nb > N_SAMPLES - 1) nb = N_SAMPLES - 1;
            nbound[re] = nb;
        }
    }
}

// ------------------------------------------------- res materialization (incremental) + ssq partials
__global__ __launch_bounds__(256) void res1_kernel(const double* par, const int* nbound,
                                                   float* res, double* dssq_part)
{
    int re = blockIdx.y;
    int tile = blockIdx.x;
    int n0 = tile * R1TILE;
    int tid = threadIdx.x;
    float* resc = res + (size_t)re * N_SAMPLES;
    if (n0 > nbound[re]) {                       // fully decayed: zero-fill
        ((float4*)(resc + n0))[tid] = float4{0.f, 0.f, 0.f, 0.f};
        if (tid == 0) dssq_part[re * R1TILES + tile] = 0.0;
        return;
    }
    __shared__ double s_om[16], s_phi[16], s_xd[16], s_coef[16];
    __shared__ float s_drev[16], s_decf[16];
    if (tid < 16) {
        int pi = re * 16 + tid;
        double xd = par[pi], om = par[512 + pi];
        s_xd[tid] = xd; s_om[tid] = om;
        s_phi[tid] = par[1024 + pi]; s_coef[tid] = par[1536 + pi];
        s_drev[tid] = (float)(om * DT_F64 * INV2PI);   // < 0.77 rev/step
        s_decf[tid] = (float)exp(-xd * DT_F64);
    }
    __syncthreads();
    int ns = n0 + tid * 4;
    double t0 = (double)ns * DT_F64;
    float p[16], cd[16], drev[16], decf[16];
#pragma unroll
    for (int o = 0; o < 16; ++o) {
        double arg = s_om[o] * t0 - s_phi[o];
        double rev = arg * INV2PI;
        rev -= rint(rev);
        p[o] = (float)rev;                              // [-0.5, 0.5] revolutions
        cd[o] = (float)s_coef[o] * expf((float)(-s_xd[o] * t0));
        drev[o] = s_drev[o]; decf[o] = s_decf[o];
    }
    float vals[4];
    double ssq = 0.0;
#pragma unroll
    for (int j = 0; j < 4; ++j) {
        float acc = 0.f;
#pragma unroll
        for (int o = 0; o < 16; ++o) {
            acc += cd[o] * __builtin_amdgcn_cosf(p[o]);  // cos(2*pi*p)
            cd[o] *= decf[o];
            float pn = p[o] + drev[o];
            p[o] = pn - floorf(pn);
        }
        int n = ns + j;
        if (n < 10) acc *= (float)n * (1.0f / 9.0f);     // ramp
        vals[j] = acc;
        ssq += (double)acc * (double)acc;
    }
    *(float4*)(resc + ns) = float4{vals[0], vals[1], vals[2], vals[3]};
    __shared__ double rb[256];
    rb[tid] = ssq; __syncthreads();
    for (int st = 128; st > 0; st >>= 1) { if (tid < st) rb[tid] += rb[tid + st]; __syncthreads(); }
    if (tid == 0) dssq_part[re * R1TILES + tile] = rb[0];
}

// ------------------------------------------------- normalize + support scan
__global__ __launch_bounds__(256) void res2_kernel(float* res, const double* dssq_part,
                                                   const int* nbound, int* rsup)
{
    int re = blockIdx.y;
    int n0 = blockIdx.x * R1TILE;
    if (n0 > nbound[re]) return;                 // region is exact zeros
    int tid = threadIdx.x;
    double ssq = 0.0;
    for (int j = 0; j < R1TILES; ++j) ssq += dssq_part[re * R1TILES + j];
    float inv = (float)(1.0 / (sqrt(ssq) + 1e-8));
    float* resc = res + (size_t)re * N_SAMPLES;
    int n = n0 + tid * 4;
    float4 v = *(float4*)(resc + n);
    v.x *= inv; v.y *= inv; v.z *= inv; v.w *= inv;
    *(float4*)(resc + n) = v;
    int mi = 0;
    if (fabsf(v.x) > 1e-10f) mi = n;
    if (fabsf(v.y) > 1e-10f) mi = n + 1;
    if (fabsf(v.z) > 1e-10f) mi = n + 2;
    if (fabsf(v.w) > 1e-10f) mi = n + 3;
    __shared__ int ib[256];
    ib[tid] = mi; __syncthreads();
    for (int st = 128; st > 0; st >>= 1) { if (tid < st) ib[tid] = max(ib[tid], ib[tid + st]); __syncthreads(); }
    if (tid == 0 && ib[0] > 0) atomicMax(&rsup[re], ib[0]);
}

// ------------------------------------------------- routed_c (16-tap sparse conv) + cs
__global__ __launch_bounds__(256) void conv1_kernel(const float* impulse, const float* routed,
                                                    float* routed_c, const int* gflag, void* out)
{
    int f32f = gflag[0];
    int n = blockIdx.x * 256 + threadIdx.x;
    int q = n >> 7, s = n & 127;
    int dkmax = min(q, 15);
    float cs = 0.f;
    for (int c = 0; c < CPD; ++c) {
        const float* ro = routed + c * FRAMES;
        const float* im = impulse + c * WIN + s;
        float acc = 0.f;
        for (int dk = 0; dk <= dkmax; ++dk)
            acc += ro[q - dk] * im[dk << 7];
        routed_c[(size_t)c * N_SAMPLES + n] = acc;
        cs += acc;
    }
    stv(out, OUT_CS_OFF + n, cs, f32f);
}

// ------------------------------------------------- zero g (atomics accumulate into it)
__global__ __launch_bounds__(256) void zero_g_kernel(float4* g)
{
    g[blockIdx.x * 256 + threadIdx.x] = float4{0.f, 0.f, 0.f, 0.f};
}

// ------------------------------------------------- g = impulse (x) res  (2048-tap FIR)
// 4-way tap split for parallelism; swizzled LDS window (j -> j + (j>>5)) so
// lane-stride-8 reads hit every bank exactly 2x (free on CDNA4).
__global__ __launch_bounds__(256) void fir_kernel(const float* res, const float* impulse,
                                                  const int* rsup, float* g)
{
    int re = blockIdx.y;
    int tile = blockIdx.x >> 2, s = blockIdx.x & 3;
    int m0 = tile * TILE_M;
    if (m0 > rsup[re] + (WIN - 1) - TAPS * s) return;   // split's res range fully decayed
    int tid = threadIdx.x;
    __shared__ float imp_s[TAPS];
    __shared__ float W[2640];                           // 2560 + swizzle pad
    const float* impc = impulse + (re >> 1) * WIN;
    const float* resc = res + (size_t)re * N_SAMPLES;
    for (int i = tid; i < TAPS; i += 256) imp_s[i] = impc[1536 - TAPS * s + i];
    int gbase = m0 - (WIN - 1) + s * TAPS;
    for (int i = tid; i < 2560; i += 256) {
        int gi = gbase + i;
        float v = (gi >= 0 && gi < N_SAMPLES) ? resc[gi] : 0.0f;
        W[i + (i >> 5)] = v;
    }
    __syncthreads();
    int base = tid * 8;
    float acc[8] = {0,0,0,0,0,0,0,0};
    float w[16];
#pragma unroll
    for (int k = 0; k < 8; ++k) { int j = base + k; w[k] = W[j + (j >> 5)]; }
    for (int p = 0; p < TAPS; p += 8) {
#pragma unroll
        for (int k = 0; k < 8; ++k) { int j = base + p + 8 + k; w[8 + k] = W[j + (j >> 5)]; }
#pragma unroll
        for (int u = 0; u < 8; ++u) {
            float im = imp_s[511 - p - u];              // wave-uniform broadcast
#pragma unroll
            for (int i = 0; i < 8; ++i) acc[i] += im * w[u + i];
        }
#pragma unroll
        for (int k = 0; k < 8; ++k) w[k] = w[8 + k];
    }
    float* gc = g + (size_t)re * N_SAMPLES + m0 + base;
#pragma unroll
    for (int i = 0; i < 8; ++i) atomicAdd(gc + i, acc[i]);
}

// ------------------------------------------------- g (f32) -> gh (bf16), halves final's traffic
__global__ __launch_bounds__(256) void g2h_kernel(const float* g, bf16* gh)
{
    int i4 = blockIdx.x * 256 + threadIdx.x;
    float4 v = ((const float4*)g)[i4];
    union { bf16 b[4]; ushort4 u; } t;
    t.b[0] = __float2bfloat16(v.x); t.b[1] = __float2bfloat16(v.y);
    t.b[2] = __float2bfloat16(v.z); t.b[3] = __float2bfloat16(v.w);
    ((ushort4*)gh)[i4] = t.u;
}

// ------------------------------------------------- conv = up (x) g, deform mix, tanh sum
// 64 samples x 4 r-groups per block -> 1024 blocks (4/CU), LDS reduce over r-groups.
__global__ __launch_bounds__(256) void final_kernel(const bf16* gh, const float* routed,
        const float* routed_c, const float* dcur, const float* mixg, const int* rsup,
        const int* gflag, void* out)
{
    __shared__ float routed_s[N_RES * FRAMES];     // 32 KB
    __shared__ float dcur_s[2 * DEF_FRAMES];
    __shared__ float mix_s[48];
    __shared__ int sup_s[NRE];
    __shared__ float part[256];
    int tid = threadIdx.x;
    int f32f = gflag[0];
    for (int i = tid; i < N_RES * FRAMES; i += 256) routed_s[i] = routed[i];
    for (int i = tid; i < 2 * DEF_FRAMES; i += 256) dcur_s[i] = dcur[i];
    if (tid < 48) mix_s[tid] = mixg[tid];
    if (tid < NRE) sup_s[tid] = rsup[tid] + (WIN - 1);
    __syncthreads();
    int nl = tid & 63, rg = tid >> 6;
    int n = blockIdx.x * 64 + nl;
    // jax.image.resize linear, half-pixel centers, edge clamp
    float xc = ((float)n + 0.5f) * (1.0f / 256.0f) - 0.5f;
    float fl = floorf(xc);
    int i0 = (int)fl;
    float wfr = xc - fl;
    int ia = min(max(i0, 0), DEF_FRAMES - 1);
    int ib2 = min(max(i0 + 1, 0), DEF_FRAMES - 1);
    float d0 = dcur_s[ia] * (1.0f - wfr) + dcur_s[ib2] * wfr;
    float d1 = dcur_s[DEF_FRAMES + ia] * (1.0f - wfr) + dcur_s[DEF_FRAMES + ib2] * wfr;
    int khi = n >> 7;
    float partial = 0.f;
    for (int rr = 0; rr < 4; ++rr) {
        int r = rg * 4 + rr;
        const bf16* g0 = gh + (size_t)(r * 2) * N_SAMPLES;
        const bf16* g1 = gh + (size_t)(r * 2 + 1) * N_SAMPLES;
        int sup = max(sup_s[r * 2], sup_s[r * 2 + 1]);
        int lo = n - sup;
        int klo = (lo <= 0) ? 0 : ((lo + 127) >> 7);
        const float* ro = routed_s + r * FRAMES;
        float c0 = 0.f, c1 = 0.f;
        for (int k = klo; k <= khi; ++k) {
            float rv = ro[k];
            int idx = n - (k << 7);
            c0 += rv * __bfloat162float(g0[idx]);
            c1 += rv * __bfloat162float(g1[idx]);
        }
        float xmix = d0 * c0 + d1 * c1;
        float xf = mix_s[r] * routed_c[(size_t)r * N_SAMPLES + n] + mix_s[16 + r] * xmix;
        partial += tanhf(xf * mix_s[32 + r]);
    }
    part[tid] = partial;
    __syncthreads();
    if (tid < 64) {
        float ssum = part[tid] + part[tid + 64] + part[tid + 128] + part[tid + 192];
        stv(out, OUT_SUM_OFF + blockIdx.x * 64 + tid, ssum, f32f);
    }
}

extern "C" void kernel_launch(void* const* d_in, const int* in_sizes, int n_in,
                              void* d_out, int out_size, void* d_ws, size_t ws_size,
                              hipStream_t stream)
{
    const void* ctrl    = d_in[0];
    const void* defo    = d_in[1];
    const void* noise   = d_in[2];
    const void* attack  = d_in[3];
    const void* router  = d_in[4];
    const void* mix     = d_in[5];
    const void* gains   = d_in[6];
    const void* damping = d_in[7];
    const void* mass    = d_in[8];
    const void* tension = d_in[9];
    const void* x0in    = d_in[10];
    const void* amps    = d_in[11];

    char* ws = (char*)d_ws;
    double* par       = (double*)(ws);             // 2048 d  -> 16384
    double* dssq_part = (double*)(ws + 16384);     // 2048 d  -> 32768
    int* gflag        = (int*)(ws + 32768);        //         -> 32896
    int* rsup         = (int*)(ws + 32896);        // 32 i    -> 33024
    int* nbound       = (int*)(ws + 33024);        // 32 i    -> 33152
    float* mixg       = (float*)(ws + 33152);      // 48 f    -> 33344
    float* dcur       = (float*)(ws + 33344);      // 512 f   -> 35392
    float* routed     = (float*)(ws + 35456);      // 8192 f  -> 68224
    float* impulse    = (float*)(ws + 68224);      // 32768 f -> 199296 (pad to 262144)
    float* res        = (float*)(ws + 262144);     // 32*65536 f (8 MB) -> 8650752
    float* g          = (float*)(ws + 8650752);    // 32*65536 f (8 MB) -> 17039360
    float* routed_c   = (float*)(ws + 17039360);   // 16*65536 f (4 MB) -> 21233664
    bf16* gh          = (bf16*)res;                // aliases res (dead after fir): 4 MB

    prep_kernel<<<dim3(98), dim3(256), 0, stream>>>(
        ctrl, defo, noise, attack, router, mix, gains, damping, mass, tension,
        x0in, amps, par, impulse, routed, dcur, mixg, rsup, nbound, gflag, d_out);
    res1_kernel<<<dim3(R1TILES, NRE), dim3(256), 0, stream>>>(par, nbound, res, dssq_part);
    res2_kernel<<<dim3(R1TILES, NRE), dim3(256), 0, stream>>>(res, dssq_part, nbound, rsup);
    conv1_kernel<<<dim3(N_SAMPLES / 256), dim3(256), 0, stream>>>(impulse, routed, routed_c, gflag, d_out);
    zero_g_kernel<<<dim3(2048), dim3(256), 0, stream>>>((float4*)g);
    fir_kernel<<<dim3((N_SAMPLES / TILE_M) * 4, NRE), dim3(256), 0, stream>>>(res, impulse, rsup, g);
    g2h_kernel<<<dim3(2048), dim3(256), 0, stream>>>(g, gh);
    final_kernel<<<dim3(N_SAMPLES / 64), dim3(256), 0, stream>>>(gh, routed, routed_c, dcur, mixg, rsup, gflag, d_out);
}